// Round 1
// baseline (617.524 us; speedup 1.0000x reference)
//
#include <hip/hip_runtime.h>
#include <hip/hip_bf16.h>
#include <stdint.h>

#define BATCH 4
#define SEQ 2048
#define DIM 1024
#define HEADS 16
#define HD 64
#define BH (BATCH*HEADS)
#define NQKV (3*DIM)

typedef __attribute__((ext_vector_type(8))) short bf16x8;
typedef __attribute__((ext_vector_type(4))) float f32x4;

#define MFMA16(a,b,c) __builtin_amdgcn_mfma_f32_16x16x32_bf16(a,b,c,0,0,0)

__device__ inline short f2bf(float f){
    __hip_bfloat16 h = __float2bfloat16(f);
    return *reinterpret_cast<short*>(&h);
}
__device__ inline float bf2f(short s){
    unsigned u = ((unsigned)(unsigned short)s) << 16;
    float f;
    __builtin_memcpy(&f, &u, 4);
    return f;
}

// ---------------- convert x -> bf16 ----------------
__global__ void conv_bf16(const float* __restrict__ in, short* __restrict__ out, int n){
    int i = blockIdx.x*blockDim.x + threadIdx.x;
    if (i < n) out[i] = f2bf(in[i]);
}

// ---------------- transpose + convert (R x C f32) -> (C x R bf16) ----------------
__global__ void transpose_conv(const float* __restrict__ in, short* __restrict__ out, int R, int C){
    __shared__ float tile[32][33];
    int c0 = blockIdx.x*32, r0 = blockIdx.y*32;
    int tx = threadIdx.x, ty = threadIdx.y;   // block (32,8)
    #pragma unroll
    for (int dy = 0; dy < 32; dy += 8)
        tile[ty+dy][tx] = in[(size_t)(r0+ty+dy)*C + c0+tx];
    __syncthreads();
    #pragma unroll
    for (int dy = 0; dy < 32; dy += 8)
        out[(size_t)(c0+ty+dy)*R + r0+tx] = f2bf(tile[tx][ty+dy]);
}

// ---------------- m97-style GEMM: C[MxN] = A[MxK] * Bt[NxK]^T ----------------
template<int WRITE_BF16>
__global__ void gemm_bt(const short* __restrict__ A, const short* __restrict__ Bt,
                        void* __restrict__ Cout, int M, int N, int K)
{
    __shared__ short As[128*32];
    __shared__ short Bs[128*32];
    const int t = threadIdx.x;
    const int lane = t & 63, wave = t >> 6;
    const int wr = wave >> 1, wc = wave & 1;      // 2x2 waves, each 64x64
    const int nbn = N >> 7;
    const int bm = blockIdx.x / nbn, bn = blockIdx.x % nbn;
    const int m0 = bm*128, n0 = bn*128;
    const int l15 = lane & 15, lhi = lane >> 4;

    f32x4 acc[4][4];
    #pragma unroll
    for (int i=0;i<4;i++)
        #pragma unroll
        for (int j=0;j<4;j++) acc[i][j] = (f32x4){0.f,0.f,0.f,0.f};

    for (int k0 = 0; k0 < K; k0 += 32) {
        #pragma unroll
        for (int it = 0; it < 2; ++it) {
            int base = (it*256 + wave*64)*8;      // wave-uniform elem offset into LDS tile
            int off  = base + lane*8;
            int row = off >> 5, col = off & 31;
            __builtin_amdgcn_global_load_lds(
                (const __attribute__((address_space(1))) void*)(A + (size_t)(m0+row)*K + k0 + col),
                (__attribute__((address_space(3))) void*)(As + base), 16, 0, 0);
            __builtin_amdgcn_global_load_lds(
                (const __attribute__((address_space(1))) void*)(Bt + (size_t)(n0+row)*K + k0 + col),
                (__attribute__((address_space(3))) void*)(Bs + base), 16, 0, 0);
        }
        __syncthreads();
        bf16x8 a[4], b[4];
        #pragma unroll
        for (int i=0;i<4;i++)
            a[i] = *(const bf16x8*)&As[(wr*64 + i*16 + l15)*32 + lhi*8];
        #pragma unroll
        for (int j=0;j<4;j++)
            b[j] = *(const bf16x8*)&Bs[(wc*64 + j*16 + l15)*32 + lhi*8];
        #pragma unroll
        for (int i=0;i<4;i++)
            #pragma unroll
            for (int j=0;j<4;j++)
                acc[i][j] = MFMA16(a[i], b[j], acc[i][j]);
        __syncthreads();
    }

    #pragma unroll
    for (int i=0;i<4;i++)
        #pragma unroll
        for (int j=0;j<4;j++)
            #pragma unroll
            for (int jj=0;jj<4;jj++) {
                int row = m0 + wr*64 + i*16 + lhi*4 + jj;
                int col = n0 + wc*64 + j*16 + l15;
                if (WRITE_BF16)
                    ((short*)Cout)[(size_t)row*N + col] = f2bf(acc[i][j][jj]);
                else
                    ((float*)Cout)[(size_t)row*N + col] = acc[i][j][jj];
            }
}

// ---------------- RoPE + scatter ----------------
// qkvb: (B,S,3D) bf16.  Writes:
//   qb,kb: (BH, S, HD) bf16 (roped)
//   vtb:   (BH, HD, S) bf16 (transposed)
//   kout,vout: (BH, S, HD) f32 outputs
__global__ void rope_scatter(const short* __restrict__ qkvb,
                             short* __restrict__ qb, short* __restrict__ kb,
                             short* __restrict__ vtb,
                             float* __restrict__ kout, float* __restrict__ vout)
{
    int idx = blockIdx.x*blockDim.x + threadIdx.x;   // BATCH*SEQ*HEADS*32
    int i = idx & 31;
    int h = (idx >> 5) & (HEADS-1);
    int s = (idx >> 9) & (SEQ-1);
    int b = idx >> 20;
    const size_t rowbase = ((size_t)(b*SEQ + s))*NQKV + h*HD;

    float q1 = bf2f(qkvb[rowbase + i]);
    float q2 = bf2f(qkvb[rowbase + i + 32]);
    float k1 = bf2f(qkvb[rowbase + DIM + i]);
    float k2 = bf2f(qkvb[rowbase + DIM + i + 32]);
    float v1 = bf2f(qkvb[rowbase + 2*DIM + i]);
    float v2 = bf2f(qkvb[rowbase + 2*DIM + i + 32]);

    // inv_freq = BASE^(-i/32); log2(10000) = 13.287712379549449
    float inv = exp2f(-(float)i * (13.28771237954945f/32.0f));
    float ang = (float)s * inv;
    float sn, c;
    sincosf(ang, &sn, &c);

    float qr1 = q1*c - q2*sn, qr2 = q2*c + q1*sn;
    float kr1 = k1*c - k2*sn, kr2 = k2*c + k1*sn;

    size_t bh = (size_t)b*HEADS + h;
    size_t obase = (bh*SEQ + s)*HD;
    qb[obase+i]      = f2bf(qr1);
    qb[obase+i+32]   = f2bf(qr2);
    kb[obase+i]      = f2bf(kr1);
    kb[obase+i+32]   = f2bf(kr2);
    kout[obase+i]    = kr1;
    kout[obase+i+32] = kr2;
    vout[obase+i]    = v1;
    vout[obase+i+32] = v2;
    vtb[(bh*HD+i)*SEQ + s]    = f2bf(v1);
    vtb[(bh*HD+i+32)*SEQ + s] = f2bf(v2);
}

// ---------------- flash attention: 1 wave per 16 q rows ----------------
// qb,kb: (BH,S,HD) bf16; vtb: (BH,HD,S) bf16; aob: (B,S,D) bf16
__global__ void attn_kernel(const short* __restrict__ qb, const short* __restrict__ kb,
                            const short* __restrict__ vtb, short* __restrict__ aob)
{
    __shared__ short plds[4][16*32];
    const int wave = threadIdx.x >> 6, lane = threadIdx.x & 63;
    const int wg = blockIdx.x*4 + wave;
    const int bh = wg >> 7;          // 0..63
    const int qt = wg & 127;
    const int q0 = qt * 16;
    const int l15 = lane & 15, lhi = lane >> 4;
    const int b = bh >> 4, h = bh & 15;

    const size_t sbase = (size_t)bh * SEQ * HD;
    bf16x8 qf[2];
    qf[0] = *(const bf16x8*)&qb[sbase + (size_t)(q0 + l15)*HD +  0 + lhi*8];
    qf[1] = *(const bf16x8*)&qb[sbase + (size_t)(q0 + l15)*HD + 32 + lhi*8];

    f32x4 o[4];
    #pragma unroll
    for (int d=0; d<4; d++) o[d] = (f32x4){0.f,0.f,0.f,0.f};
    float mrow[4], lrow[4];
    #pragma unroll
    for (int j=0;j<4;j++){ mrow[j] = -3.0e38f; lrow[j] = 0.f; }

    short* pl = plds[wave];
    const int kv_end = q0 + 16;

    for (int kv0 = 0; kv0 < kv_end; kv0 += 32) {
        bf16x8 kf[2][2];
        #pragma unroll
        for (int p=0;p<2;p++)
            #pragma unroll
            for (int kk=0;kk<2;kk++)
                kf[p][kk] = *(const bf16x8*)&kb[sbase + (size_t)(kv0 + p*16 + l15)*HD + kk*32 + lhi*8];

        f32x4 s[2];
        #pragma unroll
        for (int p=0;p<2;p++){
            s[p] = MFMA16(qf[0], kf[p][0], ((f32x4){0.f,0.f,0.f,0.f}));
            s[p] = MFMA16(qf[1], kf[p][1], s[p]);
        }
        // scale + causal mask
        #pragma unroll
        for (int p=0;p<2;p++)
            #pragma unroll
            for (int jj=0;jj<4;jj++){
                float v = s[p][jj] * 0.125f;
                int col = kv0 + p*16 + l15;
                int row = q0 + lhi*4 + jj;
                s[p][jj] = (col > row) ? -3.0e38f : v;
            }
        // row max (across 2 parts and 16 lanes of the group)
        float pm[4];
        #pragma unroll
        for (int jj=0;jj<4;jj++) pm[jj] = fmaxf(s[0][jj], s[1][jj]);
        #pragma unroll
        for (int m=1;m<16;m<<=1)
            #pragma unroll
            for (int jj=0;jj<4;jj++) pm[jj] = fmaxf(pm[jj], __shfl_xor(pm[jj], m));
        float sc[4];
        #pragma unroll
        for (int jj=0;jj<4;jj++){
            float mn = fmaxf(mrow[jj], pm[jj]);
            sc[jj] = __expf(mrow[jj] - mn);
            mrow[jj] = mn;
        }
        float rs[4] = {0.f,0.f,0.f,0.f};
        #pragma unroll
        for (int p=0;p<2;p++)
            #pragma unroll
            for (int jj=0;jj<4;jj++){
                float e = __expf(s[p][jj] - mrow[jj]);
                s[p][jj] = e;
                rs[jj] += e;
            }
        #pragma unroll
        for (int m=1;m<16;m<<=1)
            #pragma unroll
            for (int jj=0;jj<4;jj++) rs[jj] += __shfl_xor(rs[jj], m);
        #pragma unroll
        for (int jj=0;jj<4;jj++) lrow[jj] = lrow[jj]*sc[jj] + rs[jj];
        #pragma unroll
        for (int d=0;d<4;d++)
            #pragma unroll
            for (int jj=0;jj<4;jj++) o[d][jj] *= sc[jj];

        // P (D-layout) -> LDS -> A-layout frag
        #pragma unroll
        for (int p=0;p<2;p++)
            #pragma unroll
            for (int jj=0;jj<4;jj++)
                pl[(lhi*4+jj)*32 + p*16 + l15] = f2bf(s[p][jj]);
        asm volatile("s_waitcnt lgkmcnt(0)" ::: "memory");
        bf16x8 pf = *(const bf16x8*)&pl[l15*32 + lhi*8];

        #pragma unroll
        for (int d=0;d<4;d++){
            bf16x8 vf = *(const bf16x8*)&vtb[((size_t)bh*HD + d*16 + l15)*SEQ + kv0 + lhi*8];
            o[d] = MFMA16(pf, vf, o[d]);
        }
    }

    #pragma unroll
    for (int d=0;d<4;d++)
        #pragma unroll
        for (int jj=0;jj<4;jj++){
            int row = q0 + lhi*4 + jj;
            aob[((size_t)(b*SEQ + row))*DIM + h*HD + d*16 + l15] = f2bf(o[d][jj] / lrow[jj]);
        }
}

extern "C" void kernel_launch(void* const* d_in, const int* in_sizes, int n_in,
                              void* d_out, int out_size, void* d_ws, size_t ws_size,
                              hipStream_t stream) {
    const float* x     = (const float*)d_in[0];
    const float* w_qkv = (const float*)d_in[1];
    const float* w_out = (const float*)d_in[2];
    float* out  = (float*)d_out;
    float* kout = out + (size_t)BATCH*SEQ*DIM;          // 8388608
    float* vout = kout + (size_t)BH*SEQ*HD;             // +8388608

    char* ws = (char*)d_ws;
    short* xb    = (short*)(ws + 0);                    // 16 MB
    short* wqkvT = (short*)(ws + 16777216);             // 6 MB
    short* woutT = (short*)(ws + 23068672);             // 2 MB
    short* qkvb  = (short*)(ws + 25165824);             // 48 MB (8192x3072 bf16)
    short* qb    = (short*)(ws + 75497472);             // 16 MB
    short* kb    = (short*)(ws + 92274688);             // 16 MB
    short* vtb   = (short*)(ws + 109051904);            // 16 MB
    short* aob   = (short*)(ws + 125829120);            // 16 MB

    conv_bf16<<<(BATCH*SEQ*DIM)/256, 256, 0, stream>>>(x, xb, BATCH*SEQ*DIM);
    transpose_conv<<<dim3(NQKV/32, DIM/32), dim3(32,8), 0, stream>>>(w_qkv, wqkvT, DIM, NQKV);
    transpose_conv<<<dim3(DIM/32, DIM/32), dim3(32,8), 0, stream>>>(w_out, woutT, DIM, DIM);

    gemm_bt<1><<<(8192/128)*(NQKV/128), 256, 0, stream>>>(xb, wqkvT, qkvb, 8192, NQKV, DIM);

    rope_scatter<<<(BATCH*SEQ*HEADS*32)/256, 256, 0, stream>>>(qkvb, qb, kb, vtb, kout, vout);

    attn_kernel<<<(BH*(SEQ/16))/4, 256, 0, stream>>>(qb, kb, vtb, aob);

    gemm_bt<0><<<(8192/128)*(DIM/128), 256, 0, stream>>>(aob, woutT, out, 8192, DIM, DIM);
}

// Round 2
// 411.389 us; speedup vs baseline: 1.5011x; 1.5011x over previous
//
#include <hip/hip_runtime.h>
#include <hip/hip_bf16.h>
#include <stdint.h>

#define BATCH 4
#define SEQ 2048
#define DIM 1024
#define HEADS 16
#define HD 64
#define BH (BATCH*HEADS)
#define NQKV (3*DIM)

typedef __attribute__((ext_vector_type(8))) short bf16x8;
typedef __attribute__((ext_vector_type(4))) short bf16x4;
typedef __attribute__((ext_vector_type(4))) float f32x4;

#define MFMA16(a,b,c) __builtin_amdgcn_mfma_f32_16x16x32_bf16(a,b,c,0,0,0)

__device__ inline short f2bf(float f){
    __hip_bfloat16 h = __float2bfloat16(f);
    return *reinterpret_cast<short*>(&h);
}
__device__ inline float bf2f(short s){
    unsigned u = ((unsigned)(unsigned short)s) << 16;
    float f;
    __builtin_memcpy(&f, &u, 4);
    return f;
}

// ---------------- convert x -> bf16 ----------------
__global__ void conv_bf16(const float* __restrict__ in, short* __restrict__ out, int n){
    int i = blockIdx.x*blockDim.x + threadIdx.x;
    if (i < n) out[i] = f2bf(in[i]);
}

// ---------------- transpose + convert (R x C f32) -> (C x R bf16) ----------------
__global__ void transpose_conv(const float* __restrict__ in, short* __restrict__ out, int R, int C){
    __shared__ float tile[32][33];
    int c0 = blockIdx.x*32, r0 = blockIdx.y*32;
    int tx = threadIdx.x, ty = threadIdx.y;   // block (32,8)
    #pragma unroll
    for (int dy = 0; dy < 32; dy += 8)
        tile[ty+dy][tx] = in[(size_t)(r0+ty+dy)*C + c0+tx];
    __syncthreads();
    #pragma unroll
    for (int dy = 0; dy < 32; dy += 8)
        out[(size_t)(c0+ty+dy)*R + r0+tx] = f2bf(tile[tx][ty+dy]);
}

// ---------------- m97-style GEMM: C[MxN] = A[MxK] * Bt[NxK]^T ----------------
template<int WRITE_BF16>
__global__ void gemm_bt(const short* __restrict__ A, const short* __restrict__ Bt,
                        void* __restrict__ Cout, int M, int N, int K)
{
    __shared__ short As[128*32];
    __shared__ short Bs[128*32];
    const int t = threadIdx.x;
    const int lane = t & 63, wave = t >> 6;
    const int wr = wave >> 1, wc = wave & 1;      // 2x2 waves, each 64x64
    const int nbn = N >> 7;
    const int bm = blockIdx.x / nbn, bn = blockIdx.x % nbn;
    const int m0 = bm*128, n0 = bn*128;
    const int l15 = lane & 15, lhi = lane >> 4;

    f32x4 acc[4][4];
    #pragma unroll
    for (int i=0;i<4;i++)
        #pragma unroll
        for (int j=0;j<4;j++) acc[i][j] = (f32x4){0.f,0.f,0.f,0.f};

    for (int k0 = 0; k0 < K; k0 += 32) {
        #pragma unroll
        for (int it = 0; it < 2; ++it) {
            int base = (it*256 + wave*64)*8;      // wave-uniform elem offset into LDS tile
            int off  = base + lane*8;
            int row = off >> 5, col = off & 31;
            __builtin_amdgcn_global_load_lds(
                (const __attribute__((address_space(1))) void*)(A + (size_t)(m0+row)*K + k0 + col),
                (__attribute__((address_space(3))) void*)(As + base), 16, 0, 0);
            __builtin_amdgcn_global_load_lds(
                (const __attribute__((address_space(1))) void*)(Bt + (size_t)(n0+row)*K + k0 + col),
                (__attribute__((address_space(3))) void*)(Bs + base), 16, 0, 0);
        }
        __syncthreads();
        bf16x8 a[4], b[4];
        #pragma unroll
        for (int i=0;i<4;i++)
            a[i] = *(const bf16x8*)&As[(wr*64 + i*16 + l15)*32 + lhi*8];
        #pragma unroll
        for (int j=0;j<4;j++)
            b[j] = *(const bf16x8*)&Bs[(wc*64 + j*16 + l15)*32 + lhi*8];
        #pragma unroll
        for (int i=0;i<4;i++)
            #pragma unroll
            for (int j=0;j<4;j++)
                acc[i][j] = MFMA16(a[i], b[j], acc[i][j]);
        __syncthreads();
    }

    #pragma unroll
    for (int i=0;i<4;i++)
        #pragma unroll
        for (int j=0;j<4;j++)
            #pragma unroll
            for (int jj=0;jj<4;jj++) {
                int row = m0 + wr*64 + i*16 + lhi*4 + jj;
                int col = n0 + wc*64 + j*16 + l15;
                if (WRITE_BF16)
                    ((short*)Cout)[(size_t)row*N + col] = f2bf(acc[i][j][jj]);
                else
                    ((float*)Cout)[(size_t)row*N + col] = acc[i][j][jj];
            }
}

// ---------------- RoPE + scatter ----------------
// qkvb: (B,S,3D) bf16.  Writes:
//   qb: (BH,S,HD) bf16 (roped, PRE-SCALED by 0.125*log2e)
//   kb: (BH,S,HD) bf16 (roped)
//   vtb:(BH,HD,S) bf16 (transposed)
//   kout,vout: (BH,S,HD) f32 outputs
__global__ void rope_scatter(const short* __restrict__ qkvb,
                             short* __restrict__ qb, short* __restrict__ kb,
                             short* __restrict__ vtb,
                             float* __restrict__ kout, float* __restrict__ vout)
{
    int idx = blockIdx.x*blockDim.x + threadIdx.x;   // BATCH*SEQ*HEADS*32
    int i = idx & 31;
    int h = (idx >> 5) & (HEADS-1);
    int s = (idx >> 9) & (SEQ-1);
    int b = idx >> 20;
    const size_t rowbase = ((size_t)(b*SEQ + s))*NQKV + h*HD;

    float q1 = bf2f(qkvb[rowbase + i]);
    float q2 = bf2f(qkvb[rowbase + i + 32]);
    float k1 = bf2f(qkvb[rowbase + DIM + i]);
    float k2 = bf2f(qkvb[rowbase + DIM + i + 32]);
    float v1 = bf2f(qkvb[rowbase + 2*DIM + i]);
    float v2 = bf2f(qkvb[rowbase + 2*DIM + i + 32]);

    // inv_freq = BASE^(-i/32); log2(10000) = 13.287712379549449
    float inv = exp2f(-(float)i * (13.28771237954945f/32.0f));
    float ang = (float)s * inv;
    float sn, c;
    sincosf(ang, &sn, &c);

    float qr1 = q1*c - q2*sn, qr2 = q2*c + q1*sn;
    float kr1 = k1*c - k2*sn, kr2 = k2*c + k1*sn;

    // fold softmax scale (1/8) and log2(e) into q
    const float QS = 0.125f * 1.4426950408889634f;

    size_t bh = (size_t)b*HEADS + h;
    size_t obase = (bh*SEQ + s)*HD;
    qb[obase+i]      = f2bf(qr1 * QS);
    qb[obase+i+32]   = f2bf(qr2 * QS);
    kb[obase+i]      = f2bf(kr1);
    kb[obase+i+32]   = f2bf(kr2);
    kout[obase+i]    = kr1;
    kout[obase+i+32] = kr2;
    vout[obase+i]    = v1;
    vout[obase+i+32] = v2;
    vtb[(bh*HD+i)*SEQ + s]    = f2bf(v1);
    vtb[(bh*HD+i+32)*SEQ + s] = f2bf(v2);
}

// ---------------- flash attention: 1 wave per 64 q rows, swapped QK^T ----------------
// qb,kb: (BH,S,HD) bf16; vtb: (BH,HD,S) bf16; aob: (B,S,D) bf16
#define PSTRIDE 40
__global__ __launch_bounds__(64) void attn_kernel(
        const short* __restrict__ qb, const short* __restrict__ kb,
        const short* __restrict__ vtb, short* __restrict__ aob)
{
    __shared__ short Pl[64*PSTRIDE];
    __shared__ float scl[64];

    const int lane = threadIdx.x;
    // XCD swizzle: wg%8 selects XCD; keep a bh-group (8 bh) per XCD
    const int wg = blockIdx.x;               // 2048
    const int x  = wg & 7;
    const int r  = wg >> 3;
    const int qt = r & 31;
    const int bh = (x << 3) | (r >> 5);
    const int q0 = qt * 64;
    const int l15 = lane & 15, lhi = lane >> 4;
    const int b = bh >> 4, h = bh & 15;
    const size_t sbase = (size_t)bh * SEQ * HD;

    // Q fragments: 4 row-frags x (K=64 -> 2 halves). B-frag mapping == A-frag mapping.
    bf16x8 qf[4][2];
    #pragma unroll
    for (int f=0; f<4; f++)
        #pragma unroll
        for (int kk=0; kk<2; kk++)
            qf[f][kk] = *(const bf16x8*)&qb[sbase + (size_t)(q0 + f*16 + l15)*HD + kk*32 + lhi*8];

    f32x4 o[4][4];
    #pragma unroll
    for (int f=0; f<4; f++)
        #pragma unroll
        for (int d=0; d<4; d++) o[f][d] = (f32x4){0.f,0.f,0.f,0.f};
    float mrow[4], lrow[4];
    #pragma unroll
    for (int f=0; f<4; f++){ mrow[f] = -3.0e38f; lrow[f] = 0.f; }

    const int nsteps = (q0 + 64) >> 5;

    for (int step = 0; step < nsteps; ++step) {
        const int kv0 = step << 5;
        const bool masked = (kv0 >= q0);

        bf16x8 kf[2][2];
        #pragma unroll
        for (int p=0;p<2;p++)
            #pragma unroll
            for (int kk=0;kk<2;kk++)
                kf[p][kk] = *(const bf16x8*)&kb[sbase + (size_t)(kv0 + p*16 + l15)*HD + kk*32 + lhi*8];

        // S^T[kv, q] = K . Q^T  (D: col=l15 -> q, row=lhi*4+jj -> kv)
        f32x4 s[4][2];
        #pragma unroll
        for (int f=0;f<4;f++)
            #pragma unroll
            for (int p=0;p<2;p++){
                s[f][p] = MFMA16(kf[p][0], qf[f][0], ((f32x4){0.f,0.f,0.f,0.f}));
                s[f][p] = MFMA16(kf[p][1], qf[f][1], s[f][p]);
            }

        if (masked) {
            #pragma unroll
            for (int f=0;f<4;f++)
                #pragma unroll
                for (int p=0;p<2;p++)
                    #pragma unroll
                    for (int jj=0;jj<4;jj++){
                        int kv = kv0 + p*16 + lhi*4 + jj;
                        int q  = q0 + f*16 + l15;
                        if (kv > q) s[f][p][jj] = -3.0e38f;
                    }
        }

        // per-q (=l15) tile max: 7 lane-local fmax + shfl over lhi bits
        float pm[4];
        #pragma unroll
        for (int f=0;f<4;f++){
            float a0 = fmaxf(fmaxf(s[f][0][0], s[f][0][1]), fmaxf(s[f][0][2], s[f][0][3]));
            float a1 = fmaxf(fmaxf(s[f][1][0], s[f][1][1]), fmaxf(s[f][1][2], s[f][1][3]));
            float a = fmaxf(a0, a1);
            a = fmaxf(a, __shfl_xor(a, 16));
            a = fmaxf(a, __shfl_xor(a, 32));
            pm[f] = a;
        }
        int any = 0;
        #pragma unroll
        for (int f=0;f<4;f++) any |= __any(pm[f] > mrow[f]);
        if (any) {
            #pragma unroll
            for (int f=0;f<4;f++){
                float mn = fmaxf(mrow[f], pm[f]);
                float sc = exp2f(mrow[f] - mn);
                mrow[f] = mn;
                lrow[f] *= sc;
                if (lhi == 0) scl[f*16 + l15] = sc;
            }
        }

        // P = exp2(s - m), row sums
        #pragma unroll
        for (int f=0;f<4;f++){
            float rs = 0.f;
            #pragma unroll
            for (int p=0;p<2;p++)
                #pragma unroll
                for (int jj=0;jj<4;jj++){
                    float e = exp2f(s[f][p][jj] - mrow[f]);
                    s[f][p][jj] = e;
                    rs += e;
                }
            rs += __shfl_xor(rs, 16);
            rs += __shfl_xor(rs, 32);
            lrow[f] += rs;
        }

        // write P (row-major [q][kv], stride PSTRIDE) as packed bf16x4
        #pragma unroll
        for (int f=0;f<4;f++)
            #pragma unroll
            for (int p=0;p<2;p++){
                bf16x4 pk;
                #pragma unroll
                for (int jj=0;jj<4;jj++) pk[jj] = f2bf(s[f][p][jj]);
                *(bf16x4*)&Pl[(f*16 + l15)*PSTRIDE + p*16 + lhi*4] = pk;
            }
        asm volatile("s_waitcnt lgkmcnt(0)" ::: "memory");
        __builtin_amdgcn_sched_barrier(0);

        if (any) {
            #pragma unroll
            for (int f=0;f<4;f++){
                f32x4 sc4 = *(const f32x4*)&scl[f*16 + lhi*4];
                #pragma unroll
                for (int d=0;d<4;d++)
                    #pragma unroll
                    for (int jj=0;jj<4;jj++)
                        o[f][d][jj] *= sc4[jj];
            }
        }

        // PV: o[q,d] += P[q,kv] * V^T[d,kv]
        bf16x8 pf[4];
        #pragma unroll
        for (int f=0;f<4;f++)
            pf[f] = *(const bf16x8*)&Pl[(f*16 + l15)*PSTRIDE + lhi*8];
        #pragma unroll
        for (int d=0;d<4;d++){
            bf16x8 vf = *(const bf16x8*)&vtb[((size_t)bh*HD + d*16 + l15)*SEQ + kv0 + lhi*8];
            #pragma unroll
            for (int f=0;f<4;f++)
                o[f][d] = MFMA16(pf[f], vf, o[f][d]);
        }
    }

    // final 1/l via LDS transpose (l is l15-indexed; o rows are lhi*4+jj-indexed)
    if (lhi == 0) {
        #pragma unroll
        for (int f=0;f<4;f++) scl[f*16 + l15] = lrow[f];
    }
    asm volatile("s_waitcnt lgkmcnt(0)" ::: "memory");
    __builtin_amdgcn_sched_barrier(0);

    #pragma unroll
    for (int f=0;f<4;f++){
        f32x4 l4 = *(const f32x4*)&scl[f*16 + lhi*4];
        f32x4 inv4;
        #pragma unroll
        for (int jj=0;jj<4;jj++) inv4[jj] = 1.0f / l4[jj];
        #pragma unroll
        for (int d=0;d<4;d++)
            #pragma unroll
            for (int jj=0;jj<4;jj++){
                int row = q0 + f*16 + lhi*4 + jj;
                aob[((size_t)(b*SEQ + row))*DIM + h*HD + d*16 + l15] = f2bf(o[f][d][jj] * inv4[jj]);
            }
    }
}

extern "C" void kernel_launch(void* const* d_in, const int* in_sizes, int n_in,
                              void* d_out, int out_size, void* d_ws, size_t ws_size,
                              hipStream_t stream) {
    const float* x     = (const float*)d_in[0];
    const float* w_qkv = (const float*)d_in[1];
    const float* w_out = (const float*)d_in[2];
    float* out  = (float*)d_out;
    float* kout = out + (size_t)BATCH*SEQ*DIM;          // 8388608
    float* vout = kout + (size_t)BH*SEQ*HD;             // +8388608

    char* ws = (char*)d_ws;
    short* xb    = (short*)(ws + 0);                    // 16 MB
    short* wqkvT = (short*)(ws + 16777216);             // 6 MB
    short* woutT = (short*)(ws + 23068672);             // 2 MB
    short* qkvb  = (short*)(ws + 25165824);             // 48 MB (8192x3072 bf16)
    short* qb    = (short*)(ws + 75497472);             // 16 MB
    short* kb    = (short*)(ws + 92274688);             // 16 MB
    short* vtb   = (short*)(ws + 109051904);            // 16 MB
    short* aob   = (short*)(ws + 125829120);            // 16 MB

    conv_bf16<<<(BATCH*SEQ*DIM)/256, 256, 0, stream>>>(x, xb, BATCH*SEQ*DIM);
    transpose_conv<<<dim3(NQKV/32, DIM/32), dim3(32,8), 0, stream>>>(w_qkv, wqkvT, DIM, NQKV);
    transpose_conv<<<dim3(DIM/32, DIM/32), dim3(32,8), 0, stream>>>(w_out, woutT, DIM, DIM);

    gemm_bt<1><<<(8192/128)*(NQKV/128), 256, 0, stream>>>(xb, wqkvT, qkvb, 8192, NQKV, DIM);

    rope_scatter<<<(BATCH*SEQ*HEADS*32)/256, 256, 0, stream>>>(qkvb, qb, kb, vtb, kout, vout);

    attn_kernel<<<BH*(SEQ/64), 64, 0, stream>>>(qb, kb, vtb, aob);

    gemm_bt<0><<<(8192/128)*(DIM/128), 256, 0, stream>>>(aob, woutT, out, 8192, DIM, DIM);
}

// Round 3
// 294.648 us; speedup vs baseline: 2.0958x; 1.3962x over previous
//
#include <hip/hip_runtime.h>
#include <hip/hip_bf16.h>
#include <stdint.h>

#define BATCH 4
#define SEQ 2048
#define DIM 1024
#define HEADS 16
#define HD 64
#define BH (BATCH*HEADS)
#define NQKV (3*DIM)

typedef __attribute__((ext_vector_type(8))) short bf16x8;
typedef __attribute__((ext_vector_type(4))) short bf16x4;
typedef __attribute__((ext_vector_type(4))) float f32x4;

#define MFMA16(a,b,c) __builtin_amdgcn_mfma_f32_16x16x32_bf16(a,b,c,0,0,0)

__device__ inline short f2bf(float f){
    __hip_bfloat16 h = __float2bfloat16(f);
    return *reinterpret_cast<short*>(&h);
}
__device__ inline float bf2f(short s){
    unsigned u = ((unsigned)(unsigned short)s) << 16;
    float f;
    __builtin_memcpy(&f, &u, 4);
    return f;
}

// ---------------- convert x -> bf16 ----------------
__global__ void conv_bf16(const float* __restrict__ in, short* __restrict__ out, int n){
    int i = blockIdx.x*blockDim.x + threadIdx.x;
    if (i < n) out[i] = f2bf(in[i]);
}

// ---------------- transpose + convert (R x C f32) -> (C x R bf16) ----------------
__global__ void transpose_conv(const float* __restrict__ in, short* __restrict__ out, int R, int C){
    __shared__ float tile[32][33];
    int c0 = blockIdx.x*32, r0 = blockIdx.y*32;
    int tx = threadIdx.x, ty = threadIdx.y;   // block (32,8)
    #pragma unroll
    for (int dy = 0; dy < 32; dy += 8)
        tile[ty+dy][tx] = in[(size_t)(r0+ty+dy)*C + c0+tx];
    __syncthreads();
    #pragma unroll
    for (int dy = 0; dy < 32; dy += 8)
        out[(size_t)(c0+ty+dy)*R + r0+tx] = f2bf(tile[tx][ty+dy]);
}

// ---------------- m97-style GEMM: C[MxN] = A[MxK] * Bt[NxK]^T ----------------
template<int WRITE_BF16>
__global__ void gemm_bt(const short* __restrict__ A, const short* __restrict__ Bt,
                        void* __restrict__ Cout, int M, int N, int K)
{
    __shared__ short As[128*32];
    __shared__ short Bs[128*32];
    const int t = threadIdx.x;
    const int lane = t & 63, wave = t >> 6;
    const int wr = wave >> 1, wc = wave & 1;      // 2x2 waves, each 64x64
    const int nbn = N >> 7;
    const int bm = blockIdx.x / nbn, bn = blockIdx.x % nbn;
    const int m0 = bm*128, n0 = bn*128;
    const int l15 = lane & 15, lhi = lane >> 4;

    f32x4 acc[4][4];
    #pragma unroll
    for (int i=0;i<4;i++)
        #pragma unroll
        for (int j=0;j<4;j++) acc[i][j] = (f32x4){0.f,0.f,0.f,0.f};

    for (int k0 = 0; k0 < K; k0 += 32) {
        #pragma unroll
        for (int it = 0; it < 2; ++it) {
            int base = (it*256 + wave*64)*8;      // wave-uniform elem offset into LDS tile
            int off  = base + lane*8;
            int row = off >> 5, col = off & 31;
            __builtin_amdgcn_global_load_lds(
                (const __attribute__((address_space(1))) void*)(A + (size_t)(m0+row)*K + k0 + col),
                (__attribute__((address_space(3))) void*)(As + base), 16, 0, 0);
            __builtin_amdgcn_global_load_lds(
                (const __attribute__((address_space(1))) void*)(Bt + (size_t)(n0+row)*K + k0 + col),
                (__attribute__((address_space(3))) void*)(Bs + base), 16, 0, 0);
        }
        __syncthreads();
        bf16x8 a[4], b[4];
        #pragma unroll
        for (int i=0;i<4;i++)
            a[i] = *(const bf16x8*)&As[(wr*64 + i*16 + l15)*32 + lhi*8];
        #pragma unroll
        for (int j=0;j<4;j++)
            b[j] = *(const bf16x8*)&Bs[(wc*64 + j*16 + l15)*32 + lhi*8];
        #pragma unroll
        for (int i=0;i<4;i++)
            #pragma unroll
            for (int j=0;j<4;j++)
                acc[i][j] = MFMA16(a[i], b[j], acc[i][j]);
        __syncthreads();
    }

    #pragma unroll
    for (int i=0;i<4;i++)
        #pragma unroll
        for (int j=0;j<4;j++)
            #pragma unroll
            for (int jj=0;jj<4;jj++) {
                int row = m0 + wr*64 + i*16 + lhi*4 + jj;
                int col = n0 + wc*64 + j*16 + l15;
                if (WRITE_BF16)
                    ((short*)Cout)[(size_t)row*N + col] = f2bf(acc[i][j][jj]);
                else
                    ((float*)Cout)[(size_t)row*N + col] = acc[i][j][jj];
            }
}

// ---------------- RoPE + scatter ----------------
__global__ void rope_scatter(const short* __restrict__ qkvb,
                             short* __restrict__ qb, short* __restrict__ kb,
                             short* __restrict__ vtb,
                             float* __restrict__ kout, float* __restrict__ vout)
{
    int idx = blockIdx.x*blockDim.x + threadIdx.x;   // BATCH*SEQ*HEADS*32
    int i = idx & 31;
    int h = (idx >> 5) & (HEADS-1);
    int s = (idx >> 9) & (SEQ-1);
    int b = idx >> 20;
    const size_t rowbase = ((size_t)(b*SEQ + s))*NQKV + h*HD;

    float q1 = bf2f(qkvb[rowbase + i]);
    float q2 = bf2f(qkvb[rowbase + i + 32]);
    float k1 = bf2f(qkvb[rowbase + DIM + i]);
    float k2 = bf2f(qkvb[rowbase + DIM + i + 32]);
    float v1 = bf2f(qkvb[rowbase + 2*DIM + i]);
    float v2 = bf2f(qkvb[rowbase + 2*DIM + i + 32]);

    // inv_freq = BASE^(-i/32); log2(10000) = 13.287712379549449
    float inv = exp2f(-(float)i * (13.28771237954945f/32.0f));
    float ang = (float)s * inv;
    float sn, c;
    sincosf(ang, &sn, &c);

    float qr1 = q1*c - q2*sn, qr2 = q2*c + q1*sn;
    float kr1 = k1*c - k2*sn, kr2 = k2*c + k1*sn;

    // fold softmax scale (1/8) and log2(e) into q
    const float QS = 0.125f * 1.4426950408889634f;

    size_t bh = (size_t)b*HEADS + h;
    size_t obase = (bh*SEQ + s)*HD;
    qb[obase+i]      = f2bf(qr1 * QS);
    qb[obase+i+32]   = f2bf(qr2 * QS);
    kb[obase+i]      = f2bf(kr1);
    kb[obase+i+32]   = f2bf(kr2);
    kout[obase+i]    = kr1;
    kout[obase+i+32] = kr2;
    vout[obase+i]    = v1;
    vout[obase+i+32] = v2;
    vtb[(bh*HD+i)*SEQ + s]    = f2bf(v1);
    vtb[(bh*HD+i+32)*SEQ + s] = f2bf(v2);
}

// ---------------- flash attention ----------------
// 1 wave per block; each wave does TWO complementary 32-row q-tiles (qt=pr and 63-pr)
// -> every wave executes exactly 65 kv32-steps (perfect balance, no causal tail).
// Swapped QK^T (S^T = K.Q^T) so softmax reduction is 2 shuffles; q pre-scaled by 0.125*log2e.
#define PSTRIDE 40
__global__ __launch_bounds__(64) void attn_kernel(
        const short* __restrict__ qb, const short* __restrict__ kb,
        const short* __restrict__ vtb, short* __restrict__ aob)
{
    __shared__ short Pl[32*PSTRIDE];
    __shared__ float scl[32];

    const int lane = threadIdx.x;
    const int wg = blockIdx.x;               // 2048
    const int x  = wg & 7;                   // XCD swizzle
    const int r  = wg >> 3;
    const int pr = r & 31;
    const int bh = (x << 3) | (r >> 5);
    const int l15 = lane & 15, lhi = lane >> 4;
    const int b = bh >> 4, h = bh & 15;
    const size_t sbase = (size_t)bh * SEQ * HD;

    #pragma unroll 1
    for (int part = 0; part < 2; ++part) {
        const int qt = part ? (63 - pr) : pr;
        const int q0 = qt * 32;
        const int nsteps = qt + 1;

        bf16x8 qf[2][2];
        #pragma unroll
        for (int f=0; f<2; f++)
            #pragma unroll
            for (int kk=0; kk<2; kk++)
                qf[f][kk] = *(const bf16x8*)&qb[sbase + (size_t)(q0 + f*16 + l15)*HD + kk*32 + lhi*8];

        f32x4 o[2][4];
        #pragma unroll
        for (int f=0; f<2; f++)
            #pragma unroll
            for (int d=0; d<4; d++) o[f][d] = (f32x4){0.f,0.f,0.f,0.f};
        float mrow[2], lrow[2];
        #pragma unroll
        for (int f=0; f<2; f++){ mrow[f] = -3.0e38f; lrow[f] = 0.f; }

        // prefetch K for step 0
        bf16x8 kf[2][2];
        #pragma unroll
        for (int p=0;p<2;p++)
            #pragma unroll
            for (int kk=0;kk<2;kk++)
                kf[p][kk] = *(const bf16x8*)&kb[sbase + (size_t)(p*16 + l15)*HD + kk*32 + lhi*8];

        #pragma unroll 1
        for (int step = 0; step < nsteps; ++step) {
            const int kv0 = step << 5;

            // prefetch next-step K (uniform branch)
            bf16x8 kn[2][2];
            if (step + 1 < nsteps) {
                #pragma unroll
                for (int p=0;p<2;p++)
                    #pragma unroll
                    for (int kk=0;kk<2;kk++)
                        kn[p][kk] = *(const bf16x8*)&kb[sbase + (size_t)(kv0+32 + p*16 + l15)*HD + kk*32 + lhi*8];
            }
            // current-step V loads (issue early; consumed after softmax)
            bf16x8 vf[4];
            #pragma unroll
            for (int d=0;d<4;d++)
                vf[d] = *(const bf16x8*)&vtb[((size_t)bh*HD + d*16 + l15)*SEQ + kv0 + lhi*8];

            // S^T[kv, q] = K . Q^T  (D: col=l15 -> q, row=lhi*4+jj -> kv)
            __builtin_amdgcn_s_setprio(1);
            f32x4 s[2][2];
            #pragma unroll
            for (int f=0;f<2;f++)
                #pragma unroll
                for (int p=0;p<2;p++){
                    s[f][p] = MFMA16(kf[p][0], qf[f][0], ((f32x4){0.f,0.f,0.f,0.f}));
                    s[f][p] = MFMA16(kf[p][1], qf[f][1], s[f][p]);
                }
            __builtin_amdgcn_s_setprio(0);

            if (step == nsteps-1) {   // only the diagonal tile needs masking
                #pragma unroll
                for (int f=0;f<2;f++)
                    #pragma unroll
                    for (int p=0;p<2;p++)
                        #pragma unroll
                        for (int jj=0;jj<4;jj++){
                            int kv = kv0 + p*16 + lhi*4 + jj;
                            int q  = q0 + f*16 + l15;
                            if (kv > q) s[f][p][jj] = -3.0e38f;
                        }
            }

            // per-q (=l15) tile max: 7 lane-local fmax + 2 shuffles
            float pm[2];
            #pragma unroll
            for (int f=0;f<2;f++){
                float a0 = fmaxf(fmaxf(s[f][0][0], s[f][0][1]), fmaxf(s[f][0][2], s[f][0][3]));
                float a1 = fmaxf(fmaxf(s[f][1][0], s[f][1][1]), fmaxf(s[f][1][2], s[f][1][3]));
                float a = fmaxf(a0, a1);
                a = fmaxf(a, __shfl_xor(a, 16));
                a = fmaxf(a, __shfl_xor(a, 32));
                pm[f] = a;
            }
            int any = 0;
            #pragma unroll
            for (int f=0;f<2;f++) any |= __any(pm[f] > mrow[f]);
            if (any) {
                #pragma unroll
                for (int f=0;f<2;f++){
                    float mn = fmaxf(mrow[f], pm[f]);
                    float sc = exp2f(mrow[f] - mn);
                    mrow[f] = mn;
                    lrow[f] *= sc;
                    if (lhi == 0) scl[f*16 + l15] = sc;
                }
            }

            // P = exp2(s - m), row sums
            #pragma unroll
            for (int f=0;f<2;f++){
                float rs = 0.f;
                #pragma unroll
                for (int p=0;p<2;p++)
                    #pragma unroll
                    for (int jj=0;jj<4;jj++){
                        float e = exp2f(s[f][p][jj] - mrow[f]);
                        s[f][p][jj] = e;
                        rs += e;
                    }
                rs += __shfl_xor(rs, 16);
                rs += __shfl_xor(rs, 32);
                lrow[f] += rs;
            }

            // write P (row-major [q][kv], stride PSTRIDE) as packed bf16x4
            #pragma unroll
            for (int f=0;f<2;f++)
                #pragma unroll
                for (int p=0;p<2;p++){
                    bf16x4 pk;
                    #pragma unroll
                    for (int jj=0;jj<4;jj++) pk[jj] = f2bf(s[f][p][jj]);
                    *(bf16x4*)&Pl[(f*16 + l15)*PSTRIDE + p*16 + lhi*4] = pk;
                }

            // rescale O while the ds_writes land
            if (any) {
                #pragma unroll
                for (int f=0;f<2;f++){
                    f32x4 sc4 = *(const f32x4*)&scl[f*16 + lhi*4];
                    #pragma unroll
                    for (int d=0;d<4;d++)
                        #pragma unroll
                        for (int jj=0;jj<4;jj++)
                            o[f][d][jj] *= sc4[jj];
                }
            }
            asm volatile("s_waitcnt lgkmcnt(0)" ::: "memory");
            __builtin_amdgcn_sched_barrier(0);

            // PV: o[q,d] += P[q,kv] * V^T[d,kv]
            bf16x8 pf[2];
            #pragma unroll
            for (int f=0;f<2;f++)
                pf[f] = *(const bf16x8*)&Pl[(f*16 + l15)*PSTRIDE + lhi*8];
            __builtin_amdgcn_s_setprio(1);
            #pragma unroll
            for (int d=0;d<4;d++)
                #pragma unroll
                for (int f=0;f<2;f++)
                    o[f][d] = MFMA16(pf[f], vf[d], o[f][d]);
            __builtin_amdgcn_s_setprio(0);

            if (step + 1 < nsteps) {
                #pragma unroll
                for (int p=0;p<2;p++)
                    #pragma unroll
                    for (int kk=0;kk<2;kk++)
                        kf[p][kk] = kn[p][kk];
            }
        }

        // final 1/l via LDS transpose (l is l15-indexed; o rows are lhi*4+jj-indexed)
        if (lhi == 0) {
            #pragma unroll
            for (int f=0;f<2;f++) scl[f*16 + l15] = lrow[f];
        }
        asm volatile("s_waitcnt lgkmcnt(0)" ::: "memory");
        __builtin_amdgcn_sched_barrier(0);

        #pragma unroll
        for (int f=0;f<2;f++){
            f32x4 l4 = *(const f32x4*)&scl[f*16 + lhi*4];
            f32x4 inv4;
            #pragma unroll
            for (int jj=0;jj<4;jj++) inv4[jj] = 1.0f / l4[jj];
            #pragma unroll
            for (int d=0;d<4;d++)
                #pragma unroll
                for (int jj=0;jj<4;jj++){
                    int row = q0 + f*16 + lhi*4 + jj;
                    aob[((size_t)(b*SEQ + row))*DIM + h*HD + d*16 + l15] = f2bf(o[f][d][jj] * inv4[jj]);
                }
        }
    }
}

extern "C" void kernel_launch(void* const* d_in, const int* in_sizes, int n_in,
                              void* d_out, int out_size, void* d_ws, size_t ws_size,
                              hipStream_t stream) {
    const float* x     = (const float*)d_in[0];
    const float* w_qkv = (const float*)d_in[1];
    const float* w_out = (const float*)d_in[2];
    float* out  = (float*)d_out;
    float* kout = out + (size_t)BATCH*SEQ*DIM;          // 8388608
    float* vout = kout + (size_t)BH*SEQ*HD;             // +8388608

    char* ws = (char*)d_ws;
    short* xb    = (short*)(ws + 0);                    // 16 MB
    short* wqkvT = (short*)(ws + 16777216);             // 6 MB
    short* woutT = (short*)(ws + 23068672);             // 2 MB
    short* qkvb  = (short*)(ws + 25165824);             // 48 MB (8192x3072 bf16)
    short* qb    = (short*)(ws + 75497472);             // 16 MB
    short* kb    = (short*)(ws + 92274688);             // 16 MB
    short* vtb   = (short*)(ws + 109051904);            // 16 MB
    short* aob   = (short*)(ws + 125829120);            // 16 MB

    conv_bf16<<<(BATCH*SEQ*DIM)/256, 256, 0, stream>>>(x, xb, BATCH*SEQ*DIM);
    transpose_conv<<<dim3(NQKV/32, DIM/32), dim3(32,8), 0, stream>>>(w_qkv, wqkvT, DIM, NQKV);
    transpose_conv<<<dim3(DIM/32, DIM/32), dim3(32,8), 0, stream>>>(w_out, woutT, DIM, DIM);

    gemm_bt<1><<<(8192/128)*(NQKV/128), 256, 0, stream>>>(xb, wqkvT, qkvb, 8192, NQKV, DIM);

    rope_scatter<<<(BATCH*SEQ*HEADS*32)/256, 256, 0, stream>>>(qkvb, qb, kb, vtb, kout, vout);

    attn_kernel<<<2048, 64, 0, stream>>>(qb, kb, vtb, aob);

    gemm_bt<0><<<(8192/128)*(DIM/128), 256, 0, stream>>>(aob, woutT, out, 8192, DIM, DIM);
}